// Round 12
// baseline (114.218 us; speedup 1.0000x reference)
//
#include <hip/hip_runtime.h>

// Problem constants
#define B_SIZE 16384
#define D_DIM  1024
#define T_DIM  128
#define VLn    12
#define BM     64              // rows per block
#define BKF    64              // K floats per chunk (256 B per row per chunk)
#define NCHUNK 16              // 1024 / 64
#define NTHR   512             // 8 waves
#define GRID   (B_SIZE / BM)   // 256 blocks (1/CU) — B traffic halves vs R11
#define ACHB   16384           // A-chunk: 64 rows x 256 B, linear, XOR-swizzled
#define NSLOT  4
#define SLSTR  132

typedef _Float16 half8  __attribute__((ext_vector_type(8)));
typedef __fp16   fp16x2 __attribute__((ext_vector_type(2)));
typedef float    f32x4  __attribute__((ext_vector_type(4)));

union Pack16 { fp16x2 h[4]; uint4 u; half8 v; };
union Frag   { uint4 u; half8 h; };

__device__ __forceinline__ uint4 pack8u(float4 v0, float4 v1) {
    Pack16 un;
    un.h[0] = __builtin_amdgcn_cvt_pkrtz(v0.x, v0.y);
    un.h[1] = __builtin_amdgcn_cvt_pkrtz(v0.z, v0.w);
    un.h[2] = __builtin_amdgcn_cvt_pkrtz(v1.x, v1.y);
    un.h[3] = __builtin_amdgcn_cvt_pkrtz(v1.z, v1.w);
    return un.u;
}
// build f16 A-frag from 8 consecutive f32 in LDS (32-B aligned)
__device__ __forceinline__ half8 pack8f(const float* fp) {
    const float2 a = ((const float2*)fp)[0];
    const float2 b = ((const float2*)fp)[1];
    const float2 c = ((const float2*)fp)[2];
    const float2 d = ((const float2*)fp)[3];
    Pack16 un;
    un.h[0] = __builtin_amdgcn_cvt_pkrtz(a.x, a.y);
    un.h[1] = __builtin_amdgcn_cvt_pkrtz(b.x, b.y);
    un.h[2] = __builtin_amdgcn_cvt_pkrtz(c.x, c.y);
    un.h[3] = __builtin_amdgcn_cvt_pkrtz(d.x, d.y);
    return un.v;
}

// async global->LDS DMA, 16 B/lane: LDS dest = wave-uniform base + lane*16
__device__ __forceinline__ void dma16(const float* g, void* l) {
    __builtin_amdgcn_global_load_lds(
        (const __attribute__((address_space(1))) void*)g,
        (__attribute__((address_space(3))) void*)l, 16, 0, 0);
}

#define WAITV(n) asm volatile("s_waitcnt vmcnt(" #n ")" ::: "memory")
#define SB0()    __builtin_amdgcn_sched_barrier(0)

// W fp32 [128][1024] -> f16, swizzled into MFMA B-fragment order (verified).
// Also zeroes the scalar output.
__global__ __launch_bounds__(256)
void conv_w(const float* __restrict__ W, uint4* __restrict__ Wf,
            float* __restrict__ out) {
    if (blockIdx.x == 0 && threadIdx.x == 0) out[0] = 0.0f;
    const int j    = blockIdx.x * 256 + threadIdx.x;   // 0..16383
    const int kc   = j >> 10;
    const int r    = j & 1023;
    const int g    = r >> 6;
    const int lane = r & 63;
    const int n = (g & 7) * 16 + (lane & 15);
    const int k = kc * 64 + (g >> 3) * 32 + ((lane >> 4) << 3);
    const float* src = W + (size_t)n * D_DIM + k;
    Wf[j] = pack8u(*(const float4*)src, *(const float4*)(src + 4));
}

// 256 blocks x 512 threads (8 waves). Wave w owns col-tile CT=w and ALL
// FOUR 16-row tiles (acc[4]): one B fragment feeds 4 MFMAs, so the block
// reads the full 256-KB Wf exactly once -> total B traffic 64 MB (half of
// R11's 128), via PLAIN per-wave register loads (the measured ~19 B/cy
// regime; NOT global_load_lds, the ~10.5 B/cy regime of R5/R7/R9).
// A: R7's verified width-16 DMA staging (one dma16 = 4 rows; linear 256-B
// rows; both-sides XOR swizzle fidx ^= ((row&7)<<3)), 4-slot ring, issued 3
// chunks ahead. B register ring (4 slots) loaded ONE ITERATION BEFORE use,
// and placed BEFORE issue(kc+3) in program order so consuming B(s) never
// forces retirement of younger A-DMAs (A keeps >=2 chunks in flight).
// Counted vmcnt at each chunk barrier (in-order retirement: outstanding<=N
// implies the oldest retired); never drains to 0 mid-loop.
__global__ __launch_bounds__(NTHR, 2)
void qloss_kernel(const float* __restrict__ emb,
                  const uint4* __restrict__ Wf,
                  const float* __restrict__ bias,
                  const int*   __restrict__ didx,
                  const int*   __restrict__ dmsk,
                  float*       __restrict__ out)
{
    __shared__ __align__(16) unsigned char smem[NSLOT * ACHB + 64];  // 65600 B
    float* sL   = (float*)smem;                    // [64][132] epilogue alias
    float* sRed = (float*)(smem + NSLOT * ACHB);

    const int t    = threadIdx.x;
    const int w    = t >> 6;       // 0..7: col-tile AND staging row-group
    const int lane = t & 63;
    const int m15  = lane & 15;
    const int quad = lane >> 4;
    const int r0   = blockIdx.x * BM;

    // A DMA source (R7-verified): part p in {0,1}, lane l covers row
    // 8w+4p+quad, in-row float (m15*4) ^ ((4p+quad)<<3)  [inverse swizzle]
    const float* aS0 = emb + (size_t)(r0 + 8 * w + quad) * D_DIM
                           + ((m15 * 4) ^ (quad << 3));
    const float* aS1 = emb + (size_t)(r0 + 8 * w + 4 + quad) * D_DIM
                           + ((m15 * 4) ^ ((4 + quad) << 3));
    // B frag source: k-step s, col-tile w: Wf[(s>>1)*1024 + ((s&1)*8+w)*64 + lane]
    const uint4* bP = Wf + lane;

    f32x4 acc[4];
#pragma unroll
    for (int rt = 0; rt < 4; ++rt) acc[rt] = (f32x4){0.f, 0.f, 0.f, 0.f};

    Frag bp[4];                        // B ring, slot = s & 3 (16 VGPR)

#define LOADB(s)                                                              \
    bp[(s) & 3].u = bP[(size_t)((s) >> 1) * 1024 + (((s) & 1) * 8 + w) * 64]

    auto issue = [&](int j) {          // 2 A-DMAs for chunk j -> slot j&3
        unsigned char* Ab = smem + (j & 3) * ACHB;
        dma16(aS0 + j * BKF, Ab + (8 * w) * 256);        // rows 8w..8w+3
        dma16(aS1 + j * BKF, Ab + (8 * w + 4) * 256);    // rows 8w+4..8w+7
    };

    auto compute = [&](int kc) {       // 2 k-steps x 4 row-tiles
        const float* Af = (const float*)(smem + (kc & 3) * ACHB);
#pragma unroll
        for (int st = 0; st < 2; ++st) {
            const int s = kc * 2 + st;
            const int ko = (st * 32 + quad * 8);
#pragma unroll
            for (int rt = 0; rt < 4; ++rt) {
                const int row = 16 * rt + m15;
                const float* fp = Af + row * 64 + (ko ^ ((m15 & 7) << 3));
                const half8 a = pack8f(fp);
                acc[rt] = __builtin_amdgcn_mfma_f32_16x16x32_f16(
                              a, bp[s & 3].h, acc[rt], 0, 0, 0);
            }
        }
    };

    // ---- prologue: A chunks 0..2 in flight; B steps 0,1 loaded ----
    issue(0); issue(1); issue(2);
    LOADB(0); LOADB(1);

    // ---- main loop: kc = 0..12 ----
    // queue at iter top (program order): A(kc)2 ... A(kc+2)2, B(2kc),B(2kc+1)
    // WAITV(6): <=6 outstanding => A(kc) pair retired (in-order), while
    // A(kc+1..kc+2) + next B pair may stay in flight.
#pragma unroll
    for (int kc = 0; kc < NCHUNK - 3; ++kc) {
        WAITV(6);
        SB0();
        __builtin_amdgcn_s_barrier();  // chunk kc staged everywhere; slot
        SB0();                         // (kc+3)&3 consumed at compute(kc-1)
        LOADB(2 * kc + 2);             // next chunk's B (before issue: keeps
        LOADB(2 * kc + 3);             //  A-DMAs younger than consumed B)
        issue(kc + 3);
        SB0();
        compute(kc);
    }
    // ---- tail chunks 13, 14, 15 ----
    WAITV(6); SB0(); __builtin_amdgcn_s_barrier(); SB0();
    LOADB(28); LOADB(29); compute(13);
    WAITV(4); SB0(); __builtin_amdgcn_s_barrier(); SB0();
    LOADB(30); LOADB(31); compute(14);
    WAITV(2); SB0(); __builtin_amdgcn_s_barrier(); SB0();
    compute(15);
#undef LOADB

    // ---- epilogue: logits -> sL (aliases ring; all A-reads done) ----
    __syncthreads();
    const float bv = bias[w * 16 + m15];
#pragma unroll
    for (int rt = 0; rt < 4; ++rt)
#pragma unroll
        for (int i = 0; i < 4; ++i) {
            const int row = 16 * rt + quad * 4 + i;
            sL[row * SLSTR + w * 16 + m15] = acc[rt][i] + bv;
        }
    __syncthreads();

    // softmax: 512 threads = 64 rows x 8 threads, 16 cols each
    {
        const int row = t >> 3, sub = t & 7;
        float* base = &sL[row * SLSTR + sub * 16];
        float v[16];
        *(float4*)&v[0]  = *(const float4*)(base);
        *(float4*)&v[4]  = *(const float4*)(base + 4);
        *(float4*)&v[8]  = *(const float4*)(base + 8);
        *(float4*)&v[12] = *(const float4*)(base + 12);
        float m = -1e30f;
#pragma unroll
        for (int j = 0; j < 16; ++j) m = fmaxf(m, v[j]);
#pragma unroll
        for (int off = 1; off < 8; off <<= 1) m = fmaxf(m, __shfl_xor(m, off));
        float ssum = 0.f;
#pragma unroll
        for (int j = 0; j < 16; ++j) { v[j] = __expf(v[j] - m); ssum += v[j]; }
#pragma unroll
        for (int off = 1; off < 8; off <<= 1) ssum += __shfl_xor(ssum, off);
        const float inv = 1.0f / ssum;
#pragma unroll
        for (int j = 0; j < 16; ++j) v[j] *= inv;
        *(float4*)(base)      = *(const float4*)&v[0];
        *(float4*)(base + 4)  = *(const float4*)&v[4];
        *(float4*)(base + 8)  = *(const float4*)&v[8];
        *(float4*)(base + 12) = *(const float4*)&v[12];
    }
    __syncthreads();

    // gather: 64 rows x 12 labels = 768 items (threads t and 512+t)
    float p = 0.f;
#pragma unroll
    for (int e = 0; e < 2; ++e) {
        const int item = e * 512 + t;
        if (item < BM * VLn) {
            const int gi  = r0 * VLn + item;
            const int row = item / VLn;
            const int mk  = dmsk[gi];
            const int idx = didx[gi];
            if (mk) p += sL[row * SLSTR + idx];
        }
    }
#pragma unroll
    for (int off = 1; off < 64; off <<= 1) p += __shfl_xor(p, off);
    if (lane == 0) sRed[w] = p;
    __syncthreads();
    if (t == 0) {
        float s = 0.f;
#pragma unroll
        for (int i = 0; i < 8; ++i) s += sRed[i];
        atomicAdd(out, s * (1.0f / 65536.0f));
    }
}

extern "C" void kernel_launch(void* const* d_in, const int* in_sizes, int n_in,
                              void* d_out, int out_size, void* d_ws, size_t ws_size,
                              hipStream_t stream) {
    const float* emb  = (const float*)d_in[0];
    const float* W    = (const float*)d_in[1];
    const float* bias = (const float*)d_in[2];
    const int*   didx = (const int*)d_in[3];
    const int*   dmsk = (const int*)d_in[4];
    float* out = (float*)d_out;

    uint4* Wf = (uint4*)d_ws;   // 256 KB swizzled f16 W

    conv_w<<<64, 256, 0, stream>>>(W, Wf, out);
    qloss_kernel<<<GRID, NTHR, 0, stream>>>(emb, Wf, bias, didx, dmsk, out);
}

// Round 13
// 108.370 us; speedup vs baseline: 1.0540x; 1.0540x over previous
//
#include <hip/hip_runtime.h>

// Problem constants
#define B_SIZE 16384
#define D_DIM  1024
#define T_DIM  128
#define VLn    12
#define BM     32              // rows per block
#define BK     256             // K per chunk -> 1 KB per row per chunk (linear DMA)
#define NCHUNK 4
#define NTHR   256             // 4 waves
#define GRID   (B_SIZE / BM)   // 512 blocks = 2 per CU
#define AROWF  258             // LDS A row stride in floats (256 + 2 pad)
#define AROWB  1032            // bytes
#define ABUFB  (BM * AROWB)    // 33024 B per buffer
#define SLSTR  132

typedef _Float16 half8  __attribute__((ext_vector_type(8)));
typedef __fp16   fp16x2 __attribute__((ext_vector_type(2)));
typedef float    f32x4  __attribute__((ext_vector_type(4)));

union Pack16 { fp16x2 h[4]; uint4 u; half8 v; };
union Frag   { uint4 u; half8 h; };

__device__ __forceinline__ uint4 pack8u(float4 v0, float4 v1) {
    Pack16 un;
    un.h[0] = __builtin_amdgcn_cvt_pkrtz(v0.x, v0.y);
    un.h[1] = __builtin_amdgcn_cvt_pkrtz(v0.z, v0.w);
    un.h[2] = __builtin_amdgcn_cvt_pkrtz(v1.x, v1.y);
    un.h[3] = __builtin_amdgcn_cvt_pkrtz(v1.z, v1.w);
    return un.u;
}
// build f16 A-frag from 8 consecutive f32 in LDS (8-B aligned)
__device__ __forceinline__ half8 pack8f(const float* fp) {
    const float2 a = ((const float2*)fp)[0];
    const float2 b = ((const float2*)fp)[1];
    const float2 c = ((const float2*)fp)[2];
    const float2 d = ((const float2*)fp)[3];
    Pack16 un;
    un.h[0] = __builtin_amdgcn_cvt_pkrtz(a.x, a.y);
    un.h[1] = __builtin_amdgcn_cvt_pkrtz(b.x, b.y);
    un.h[2] = __builtin_amdgcn_cvt_pkrtz(c.x, c.y);
    un.h[3] = __builtin_amdgcn_cvt_pkrtz(d.x, d.y);
    return un.v;
}

// async global->LDS DMA, 16 B/lane: LDS dest = wave-uniform base + lane*16
__device__ __forceinline__ void dma16(const float* g, void* l) {
    __builtin_amdgcn_global_load_lds(
        (const __attribute__((address_space(1))) void*)g,
        (__attribute__((address_space(3))) void*)l, 16, 0, 0);
}

#define WAITV(n) asm volatile("s_waitcnt vmcnt(" #n ")" ::: "memory")
#define SB0()    __builtin_amdgcn_sched_barrier(0)

// W fp32 [128][1024] -> f16, swizzled into MFMA B-fragment order (verified).
// Also zeroes the scalar output.
__global__ __launch_bounds__(256)
void conv_w(const float* __restrict__ W, uint4* __restrict__ Wf,
            float* __restrict__ out) {
    if (blockIdx.x == 0 && threadIdx.x == 0) out[0] = 0.0f;
    const int j    = blockIdx.x * 256 + threadIdx.x;   // 0..16383
    const int kc   = j >> 10;
    const int r    = j & 1023;
    const int g    = r >> 6;
    const int lane = r & 63;
    const int n = (g & 7) * 16 + (lane & 15);
    const int k = kc * 64 + (g >> 3) * 32 + ((lane >> 4) << 3);
    const float* src = W + (size_t)n * D_DIM + k;
    Wf[j] = pack8u(*(const float4*)src, *(const float4*)(src + 4));
}

// 512 blocks x 256 threads (4 waves) = 2 blocks/CU. Block = 32 rows x 128
// cols x full K. BEST MEASURED CONFIGURATION (109.4 us, round 11).
// Each wave computes TWO 16-row tiles with the SAME B registers (acc[2][2],
// 4 MFMA/k-step), halving total B traffic vs the per-16-row baseline.
// A: width-16 DMA staging into padded double-buffered LDS; B: depth-2
// per-k-step register ring from pre-swizzled Wf; counted-vmcnt chunk
// barriers (never drain to 0 mid-loop). Two co-resident blocks per CU form
// independent barrier groups that cover each other's DMA-completion stalls.
__global__ __launch_bounds__(NTHR, 2)
void qloss_kernel(const float* __restrict__ emb,
                  const uint4* __restrict__ Wf,
                  const float* __restrict__ bias,
                  const int*   __restrict__ didx,
                  const int*   __restrict__ dmsk,
                  float*       __restrict__ out)
{
    __shared__ __align__(16) unsigned char smem[2 * ABUFB + 32];   // 66080 B
    float* sL   = (float*)smem;                    // [32][132] epilogue alias
    float* sRed = (float*)(smem + 2 * ABUFB);

    const int t    = threadIdx.x;
    const int w    = t >> 6;
    const int lane = t & 63;
    const int m15  = lane & 15;
    const int quad = lane >> 4;
    const int r0   = blockIdx.x * BM;

    // DMA: wave w stages rows 8w..8w+7; one dma16 per row (64 lanes x 16 B)
    const float* aG0 = emb + (size_t)(r0 + 8 * w) * D_DIM + lane * 4;

    // wave w owns col-tiles CT0=2w, CT0+1 and BOTH row-groups (rows 0..15,
    // 16..31) — the same B frags feed both row-tiles.
    const int CT0 = 2 * w;
    const uint4* bP = Wf + lane;

    f32x4 acc[2][2];
#pragma unroll
    for (int rt = 0; rt < 2; ++rt)
#pragma unroll
        for (int j = 0; j < 2; ++j)
            acc[rt][j] = (f32x4){0.f, 0.f, 0.f, 0.f};

    Frag bp[3][2];                     // depth-2 per-k-step B ring (24 VGPR)

#define LOADB(s, slot)                                                        \
    do {                                                                      \
        bp[slot][0].u = bP[(size_t)((s) >> 1) * 1024 +                        \
                           (((s) & 1) * 8 + CT0 + 0) * 64];                   \
        bp[slot][1].u = bP[(size_t)((s) >> 1) * 1024 +                        \
                           (((s) & 1) * 8 + CT0 + 1) * 64];                   \
    } while (0)

    // ---- prologue: DMA chunk 0 (oldest), then B pairs s=0,1 ----
#pragma unroll
    for (int r = 0; r < 8; ++r)
        dma16(aG0 + (size_t)r * D_DIM, smem + (8 * w + r) * AROWB);
    LOADB(0, 0);
    LOADB(1, 1);
    // retire the 8 A-DMAs (oldest); keep the 4 B loads in flight
    WAITV(4);
    SB0();
    __builtin_amdgcn_s_barrier();
    SB0();

#pragma unroll
    for (int kc = 0; kc < NCHUNK; ++kc) {
        const float* bufC = (const float*)(smem + (kc & 1) * ABUFB);
        unsigned char* bufN = (unsigned char*)smem + ((kc & 1) ^ 1) * ABUFB;

        // next chunk's A-DMA first (oldest in this iteration's vmcnt window)
        if (kc + 1 < NCHUNK) {
#pragma unroll
            for (int r = 0; r < 8; ++r)
                dma16(aG0 + (size_t)r * D_DIM + (kc + 1) * BK,
                      bufN + (8 * w + r) * AROWB);
        }

        // compute chunk kc: 8 k-steps x (2 row-tiles x 2 col-tiles)
#pragma unroll
        for (int ks = 0; ks < 8; ++ks) {
            const int s = kc * 8 + ks;
            if (s + 2 < 32) LOADB(s + 2, (s + 2) % 3);
            const float* fp0 = bufC + m15 * AROWF + ks * 32 + quad * 8;
            const float* fp1 = fp0 + 16 * AROWF;
            const half8 a0 = pack8f(fp0);
            const half8 a1 = pack8f(fp1);
            const int sl = s % 3;
            acc[0][0] = __builtin_amdgcn_mfma_f32_16x16x32_f16(a0, bp[sl][0].h, acc[0][0], 0, 0, 0);
            acc[0][1] = __builtin_amdgcn_mfma_f32_16x16x32_f16(a0, bp[sl][1].h, acc[0][1], 0, 0, 0);
            acc[1][0] = __builtin_amdgcn_mfma_f32_16x16x32_f16(a1, bp[sl][0].h, acc[1][0], 0, 0, 0);
            acc[1][1] = __builtin_amdgcn_mfma_f32_16x16x32_f16(a1, bp[sl][1].h, acc[1][1], 0, 0, 0);
        }

        if (kc + 1 < NCHUNK) {
            // retire A-DMA(kc+1) (8 oldest); the unconsumed B pairs (next
            // chunk's first two steps) stay in flight across the barrier.
            WAITV(4);
            SB0();
            __builtin_amdgcn_s_barrier();
            SB0();
        }
    }
#undef LOADB

    // ---- epilogue: logits -> sL (aliases buf0; all A-reads done) ----
    __syncthreads();
    const float b0v = bias[CT0 * 16 + m15];
    const float b1v = bias[(CT0 + 1) * 16 + m15];
#pragma unroll
    for (int rt = 0; rt < 2; ++rt)
#pragma unroll
        for (int i = 0; i < 4; ++i) {
            const int row = 16 * rt + quad * 4 + i;
            sL[row * SLSTR + CT0 * 16 + m15]       = acc[rt][0][i] + b0v;
            sL[row * SLSTR + (CT0 + 1) * 16 + m15] = acc[rt][1][i] + b1v;
        }
    __syncthreads();

    // softmax: 256 threads = 32 rows x 8 threads, 16 cols each
    {
        const int row = t >> 3, sub = t & 7;
        float* base = &sL[row * SLSTR + sub * 16];
        float v[16];
        *(float4*)&v[0]  = *(const float4*)(base);
        *(float4*)&v[4]  = *(const float4*)(base + 4);
        *(float4*)&v[8]  = *(const float4*)(base + 8);
        *(float4*)&v[12] = *(const float4*)(base + 12);
        float m = -1e30f;
#pragma unroll
        for (int j = 0; j < 16; ++j) m = fmaxf(m, v[j]);
#pragma unroll
        for (int off = 1; off < 8; off <<= 1) m = fmaxf(m, __shfl_xor(m, off));
        float ssum = 0.f;
#pragma unroll
        for (int j = 0; j < 16; ++j) { v[j] = __expf(v[j] - m); ssum += v[j]; }
#pragma unroll
        for (int off = 1; off < 8; off <<= 1) ssum += __shfl_xor(ssum, off);
        const float inv = 1.0f / ssum;
#pragma unroll
        for (int j = 0; j < 16; ++j) v[j] *= inv;
        *(float4*)(base)      = *(const float4*)&v[0];
        *(float4*)(base + 4)  = *(const float4*)&v[4];
        *(float4*)(base + 8)  = *(const float4*)&v[8];
        *(float4*)(base + 12) = *(const float4*)&v[12];
    }
    __syncthreads();

    // gather: 32 rows x 12 labels = 384 items (threads t and 256+t)
    float p = 0.f;
#pragma unroll
    for (int e = 0; e < 2; ++e) {
        const int item = e * 256 + t;
        if (item < BM * VLn) {
            const int gi  = r0 * VLn + item;
            const int row = item / VLn;
            const int mk  = dmsk[gi];
            const int idx = didx[gi];
            if (mk) p += sL[row * SLSTR + idx];
        }
    }
#pragma unroll
    for (int off = 1; off < 64; off <<= 1) p += __shfl_xor(p, off);
    if (lane == 0) sRed[w] = p;
    __syncthreads();
    if (t == 0)
        atomicAdd(out, (sRed[0] + sRed[1] + sRed[2] + sRed[3]) * (1.0f / 65536.0f));
}

extern "C" void kernel_launch(void* const* d_in, const int* in_sizes, int n_in,
                              void* d_out, int out_size, void* d_ws, size_t ws_size,
                              hipStream_t stream) {
    const float* emb  = (const float*)d_in[0];
    const float* W    = (const float*)d_in[1];
    const float* bias = (const float*)d_in[2];
    const int*   didx = (const int*)d_in[3];
    const int*   dmsk = (const int*)d_in[4];
    float* out = (float*)d_out;

    uint4* Wf = (uint4*)d_ws;   // 256 KB swizzled f16 W

    conv_w<<<64, 256, 0, stream>>>(W, Wf, out);
    qloss_kernel<<<GRID, NTHR, 0, stream>>>(emb, Wf, bias, didx, dmsk, out);
}